// Round 3
// baseline (342.688 us; speedup 1.0000x reference)
//
#include <hip/hip_runtime.h>
#include <hip/hip_bf16.h>

// MeanPooling as batched GEMM: out[b,n,h] = (sum_s map[b,n,s]*doc[b,s,h]) / len[b,n]
// B=8, N=512 (M), S=4096 (K), H=1024 (N-dim). All fp32 in/out.
// R3: break the __syncthreads vmcnt(0) drain. Raw s_barrier + lgkmcnt(0) only;
// depth-2 register prefetch (two named reg sets, 2x-unrolled loop) so each
// tile's loads have a full iteration of latency cover and the newest loads
// stay in flight across the barrier (T3/T4 counted-vmcnt via compiler's
// per-value waits). 128x64 tiles (1.5 GB requested vs 2 GB at 64^2),
// 512 blocks = 2/CU, 4 waves, 1 barrier/iter.

typedef __bf16 bf16x8 __attribute__((ext_vector_type(8)));
typedef float  f32x4  __attribute__((ext_vector_type(4)));

#define MFMA16(a, b, c) __builtin_amdgcn_mfma_f32_16x16x32_bf16(a, b, c, 0, 0, 0)

constexpr int Bsz = 8;
constexpr int Nn  = 512;   // nodes (M)
constexpr int Ss  = 4096;  // seq   (K)
constexpr int Hh  = 1024;  // hidden(N)

constexpr int BM = 128, BN = 64, BK = 32;
constexpr int LDK = 40;          // 80 B row stride: 2-way max on b128 frag reads
constexpr int NT  = Ss / BK;     // 128 K-steps (even, required by 2x unroll)
constexpr int NWG = Bsz * (Nn / BM) * (Hh / BN);  // 8*4*16 = 512

struct StageRegs {
    f32x4 a[4];   // A: 16 consecutive k (fp32) of one node row
    float b[8];   // B: 8 k (stride Hh) of one h column
};

__device__ __forceinline__ void issue_loads(StageRegs& r, const float* Ab, const float* Bb,
                                            int s0, int ra, int ka, int hbb, int kb) {
    const float* ap = Ab + (size_t)ra * Ss + s0 + ka;
    #pragma unroll
    for (int i = 0; i < 4; i++) r.a[i] = *(const f32x4*)(ap + i * 4);
    const float* bp = Bb + (size_t)(s0 + kb * 8) * Hh + hbb;
    #pragma unroll
    for (int j = 0; j < 8; j++) r.b[j] = bp[(size_t)j * Hh];
}

__device__ __forceinline__ void write_lds(__bf16* As, __bf16* Bs, const StageRegs& r,
                                          int ra, int ka, int hbb, int kb) {
    bf16x8 v0, v1, w;
    #pragma unroll
    for (int i = 0; i < 8; i++) {
        v0[i] = (__bf16)r.a[i >> 2][i & 3];
        v1[i] = (__bf16)r.a[2 + (i >> 2)][i & 3];
        w[i]  = (__bf16)r.b[i];
    }
    *(bf16x8*)&As[ra * LDK + ka]     = v0;
    *(bf16x8*)&As[ra * LDK + ka + 8] = v1;
    *(bf16x8*)&Bs[hbb * LDK + kb * 8] = w;
}

__device__ __forceinline__ void compute(const __bf16* As, const __bf16* Bs,
                                        f32x4 acc[4][2], int wr, int wc, int l15, int l4) {
    bf16x8 aF[4], bF[2];
    #pragma unroll
    for (int m = 0; m < 4; m++)
        aF[m] = *(const bf16x8*)&As[(wr * 64 + m * 16 + l15) * LDK + l4 * 8];
    #pragma unroll
    for (int n = 0; n < 2; n++)
        bF[n] = *(const bf16x8*)&Bs[(wc * 32 + n * 16 + l15) * LDK + l4 * 8];
    #pragma unroll
    for (int m = 0; m < 4; m++)
        #pragma unroll
        for (int n = 0; n < 2; n++)
            acc[m][n] = MFMA16(aF[m], bF[n], acc[m][n]);
}

__global__ __launch_bounds__(256, 2)
void mean_pool_gemm(const float* __restrict__ doc,   // [B,S,H]
                    const float* __restrict__ map,   // [B,N,S]
                    const float* __restrict__ len,   // [B,N]
                    float* __restrict__ out)         // [B,N,H]
{
    __shared__ __align__(16) __bf16 As0[BM * LDK], As1[BM * LDK];  // 10 KB each
    __shared__ __align__(16) __bf16 Bs0[BN * LDK], Bs1[BN * LDK];  // 5 KB each

    // XCD swizzle: 512 blocks, 64/XCD == exactly one batch per XCD.
    const int blk = (blockIdx.x & 7) * (NWG / 8) + (blockIdx.x >> 3);
    const int b   = blk >> 6;
    const int rem = blk & 63;
    const int mt  = rem >> 4;            // 0..3
    const int ht  = rem & 15;            // 0..15
    const int n0  = mt * BM;
    const int h0  = ht * BN;

    const int tid  = threadIdx.x;
    const int wave = tid >> 6;
    const int lane = tid & 63;
    const int wr   = wave >> 1;          // 0/1 -> 64 rows each
    const int wc   = wave & 1;           // 0/1 -> 32 cols each
    const int l15  = lane & 15;
    const int l4   = lane >> 4;

    const float* Ab = map + (size_t)b * Nn * Ss + (size_t)n0 * Ss;
    const float* Bb = doc + (size_t)b * Ss * Hh + h0;

    // A staging: row ra (0..127), k-offset ka in {0,16}
    const int ra = tid >> 1;
    const int ka = (tid & 1) * 16;
    // B staging: column hbb (0..63), k-block kb (0..3) of 8
    const int hbb = tid & 63;
    const int kb  = tid >> 6;

    StageRegs r0, r1;
    f32x4 acc[4][2] = {};

    // ---- prologue: tiles 0,1 in flight; tile 0 -> L0
    issue_loads(r0, Ab, Bb, 0,  ra, ka, hbb, kb);
    issue_loads(r1, Ab, Bb, BK, ra, ka, hbb, kb);
    write_lds(As0, Bs0, r0, ra, ka, hbb, kb);   // waits r0's loads only (r1 stays in flight)
    asm volatile("s_waitcnt lgkmcnt(0)" ::: "memory");
    __builtin_amdgcn_s_barrier();

    for (int t = 0; t < NT; t += 2) {
        {   // half A: load t+2 -> r0 | write tile t+1 (r1) -> L1 | compute tile t (L0)
            const int s2 = (t + 2 < NT ? t + 2 : NT - 1) * BK;
            issue_loads(r0, Ab, Bb, s2, ra, ka, hbb, kb);
            write_lds(As1, Bs1, r1, ra, ka, hbb, kb);   // vmcnt counted: r0's 12 newest stay out
            compute(As0, Bs0, acc, wr, wc, l15, l4);
            asm volatile("s_waitcnt lgkmcnt(0)" ::: "memory");
            __builtin_amdgcn_s_barrier();
        }
        {   // half B: load t+3 -> r1 | write tile t+2 (r0) -> L0 | compute tile t+1 (L1)
            const int s3 = (t + 3 < NT ? t + 3 : NT - 1) * BK;
            issue_loads(r1, Ab, Bb, s3, ra, ka, hbb, kb);
            write_lds(As0, Bs0, r0, ra, ka, hbb, kb);
            compute(As1, Bs1, acc, wr, wc, l15, l4);
            asm volatile("s_waitcnt lgkmcnt(0)" ::: "memory");
            __builtin_amdgcn_s_barrier();
        }
    }

    // ---- epilogue: divide by nodes_len, store
    // C/D layout (16x16): col = lane&15, row = (lane>>4)*4 + j   [m89-verified]
    const float* lenb = len + b * Nn + n0 + wr * 64;
    float* ob = out + (size_t)b * Nn * Hh + (size_t)(n0 + wr * 64) * Hh + h0 + wc * 32;
    #pragma unroll
    for (int m = 0; m < 4; m++) {
        float inv[4];
        #pragma unroll
        for (int j = 0; j < 4; j++) inv[j] = 1.0f / lenb[m * 16 + l4 * 4 + j];
        #pragma unroll
        for (int n = 0; n < 2; n++) {
            #pragma unroll
            for (int j = 0; j < 4; j++) {
                const int row = m * 16 + l4 * 4 + j;
                ob[(size_t)row * Hh + n * 16 + l15] = acc[m][n][j] * inv[j];
            }
        }
    }
}

extern "C" void kernel_launch(void* const* d_in, const int* in_sizes, int n_in,
                              void* d_out, int out_size, void* d_ws, size_t ws_size,
                              hipStream_t stream) {
    const float* doc = (const float*)d_in[0];  // [B,S,H]
    const float* map = (const float*)d_in[1];  // [B,N,S]
    const float* len = (const float*)d_in[2];  // [B,N]
    float* out = (float*)d_out;                // [B,N,H]

    dim3 grid(NWG);     // 512 blocks = 2 per CU
    dim3 block(256);
    hipLaunchKernelGGL(mean_pool_gemm, grid, block, 0, stream, doc, map, len, out);
}

// Round 5
// 324.679 us; speedup vs baseline: 1.0555x; 1.0555x over previous
//
#include <hip/hip_runtime.h>
#include <hip/hip_bf16.h>

// MeanPooling as batched GEMM: out[b,n,h] = (sum_s map[b,n,s]*doc[b,s,h]) / len[b,n]
// B=8, N=512 (M), S=4096 (K), H=1024 (N-dim). All fp32 in/out.
// R4 (resubmit after broker timeout): requested-bytes minimization. Measured
// service rate ~21 B/cy/CU means time ~= requested bytes / 12.9 TB/s. 256x256
// tiles cut requested bytes from 2.1 GB (64^2) to 536 MB. Split-K=4 restores
// grid=256 (1 block/CU, 8 waves). fp32 atomicAdd epilogue with 1/len folded
// into each partial (division distributes over the split sum). d_out zeroed
// via hipMemsetAsync (graph-capture safe).

typedef __bf16 bf16x8 __attribute__((ext_vector_type(8)));
typedef float  f32x4  __attribute__((ext_vector_type(4)));

#define MFMA16(a, b, c) __builtin_amdgcn_mfma_f32_16x16x32_bf16(a, b, c, 0, 0, 0)

constexpr int Bsz = 8;
constexpr int Nn  = 512;   // nodes (M)
constexpr int Ss  = 4096;  // seq   (K)
constexpr int Hh  = 1024;  // hidden(N)

constexpr int BM = 256, BN = 256, BK = 32;
constexpr int SPLITK = 4;
constexpr int KC  = Ss / SPLITK;   // 1024 k per block
constexpr int NT  = KC / BK;       // 32 K-steps
constexpr int LDK = 40;            // 80 B row stride (bf16), 16B-aligned
constexpr int NWG = Bsz * (Nn / BM) * (Hh / BN) * SPLITK;  // 8*2*4*4 = 256

struct StageRegs {
    f32x4 a[4];    // A: 16 consecutive k (fp32) of one node row
    float b[16];   // B: 16 k (stride Hh) of one h column
};

__device__ __forceinline__ void issue_loads(StageRegs& r, const float* Ab, const float* Bb,
                                            int s0, int ra, int ka, int hb, int kc) {
    const float* ap = Ab + (size_t)ra * Ss + s0 + ka;
    #pragma unroll
    for (int i = 0; i < 4; i++) r.a[i] = *(const f32x4*)(ap + i * 4);
    const float* bp = Bb + (size_t)(s0 + kc * 16) * Hh + hb;
    #pragma unroll
    for (int j = 0; j < 16; j++) r.b[j] = bp[(size_t)j * Hh];
}

__device__ __forceinline__ void write_lds(__bf16* As, __bf16* Bs, const StageRegs& r,
                                          int ra, int ka, int hb, int kc) {
    bf16x8 v0, v1, w0, w1;
    #pragma unroll
    for (int i = 0; i < 8; i++) {
        v0[i] = (__bf16)r.a[i >> 2][i & 3];
        v1[i] = (__bf16)r.a[2 + (i >> 2)][i & 3];
        w0[i] = (__bf16)r.b[i];
        w1[i] = (__bf16)r.b[8 + i];
    }
    *(bf16x8*)&As[ra * LDK + ka]          = v0;
    *(bf16x8*)&As[ra * LDK + ka + 8]      = v1;
    *(bf16x8*)&Bs[hb * LDK + kc * 16]     = w0;
    *(bf16x8*)&Bs[hb * LDK + kc * 16 + 8] = w1;
}

__device__ __forceinline__ void compute(const __bf16* As, const __bf16* Bs,
                                        f32x4 acc[8][4], int wr, int wc, int l15, int l4) {
    bf16x8 aF[8], bF[4];
    #pragma unroll
    for (int m = 0; m < 8; m++)
        aF[m] = *(const bf16x8*)&As[(wr * 128 + m * 16 + l15) * LDK + l4 * 8];
    #pragma unroll
    for (int n = 0; n < 4; n++)
        bF[n] = *(const bf16x8*)&Bs[(wc * 64 + n * 16 + l15) * LDK + l4 * 8];
    #pragma unroll
    for (int m = 0; m < 8; m++)
        #pragma unroll
        for (int n = 0; n < 4; n++)
            acc[m][n] = MFMA16(aF[m], bF[n], acc[m][n]);
}

__global__ __launch_bounds__(512, 1)
void mean_pool_gemm(const float* __restrict__ doc,   // [B,S,H]
                    const float* __restrict__ map,   // [B,N,S]
                    const float* __restrict__ len,   // [B,N]
                    float* out)                      // [B,N,H] (atomicAdd target)
{
    __shared__ __align__(16) __bf16 As[2][BM * LDK];  // 2 x 20 KB
    __shared__ __align__(16) __bf16 Bs[2][BN * LDK];  // 2 x 20 KB

    // XCD swizzle: 256 blocks; XCD x gets logical 32x..32x+31 == all of batch x
    // (incl. its split-K siblings -> L2-local atomics, shared panels).
    const int logical = (blockIdx.x & 7) * (NWG / 8) + (blockIdx.x >> 3);
    const int b  = logical >> 5;
    const int s  = (logical >> 3) & 3;   // k-chunk
    const int mt = (logical >> 2) & 1;   // node tile
    const int ht = logical & 3;          // h tile
    const int n0 = mt * BM, h0 = ht * BN, k0 = s * KC;

    const int tid  = threadIdx.x;
    const int wave = tid >> 6;
    const int lane = tid & 63;
    const int wr   = wave >> 2;          // 0..1 -> 128 rows
    const int wc   = wave & 3;           // 0..3 -> 64 cols
    const int l15  = lane & 15;
    const int l4   = lane >> 4;

    const float* Ab = map + (size_t)b * Nn * Ss + (size_t)n0 * Ss + k0;
    const float* Bb = doc + (size_t)b * Ss * Hh + (size_t)k0 * Hh + h0;

    // A staging: lane-pair shares row ra (0..255); ka in {0,16}
    const int ra = tid >> 1;
    const int ka = (tid & 1) * 16;
    // B staging: lane-pair shares column hb (0..255); kc in {0,1} (16 k each)
    const int hb = tid >> 1;
    const int kc = tid & 1;

    StageRegs r;
    f32x4 acc[8][4] = {};

    // ---- prologue: tile 0 -> buf 0
    issue_loads(r, Ab, Bb, 0, ra, ka, hb, kc);
    write_lds(As[0], Bs[0], r, ra, ka, hb, kc);
    asm volatile("s_waitcnt lgkmcnt(0)" ::: "memory");
    __builtin_amdgcn_s_barrier();

    int cur = 0;
    for (int t = 0; t < NT; ++t) {
        if (t + 1 < NT)
            issue_loads(r, Ab, Bb, (t + 1) * BK, ra, ka, hb, kc);   // ~350 cy cover under compute
        compute(As[cur], Bs[cur], acc, wr, wc, l15, l4);
        if (t + 1 < NT) {
            // writing buf[cur^1]: its last readers finished before barrier(t-1) -> safe
            write_lds(As[cur ^ 1], Bs[cur ^ 1], r, ra, ka, hb, kc);
            asm volatile("s_waitcnt lgkmcnt(0)" ::: "memory");
            __builtin_amdgcn_s_barrier();
            cur ^= 1;
        }
    }

    // ---- epilogue: atomicAdd partial * (1/len) — division distributes over split-K sum
    // C/D layout (16x16): col = lane&15, row = (lane>>4)*4 + j   [m89-verified]
    const float* lenp = len + b * Nn + n0 + wr * 128;
    float* ob = out + (size_t)b * Nn * Hh + (size_t)(n0 + wr * 128) * Hh + h0 + wc * 64;
    #pragma unroll
    for (int m = 0; m < 8; m++) {
        const int row_l = m * 16 + l4 * 4;
        float inv[4];
        #pragma unroll
        for (int j = 0; j < 4; j++) inv[j] = 1.0f / lenp[row_l + j];
        #pragma unroll
        for (int n = 0; n < 4; n++) {
            #pragma unroll
            for (int j = 0; j < 4; j++)
                atomicAdd(&ob[(size_t)(row_l + j) * Hh + n * 16 + l15], acc[m][n][j] * inv[j]);
        }
    }
}

extern "C" void kernel_launch(void* const* d_in, const int* in_sizes, int n_in,
                              void* d_out, int out_size, void* d_ws, size_t ws_size,
                              hipStream_t stream) {
    const float* doc = (const float*)d_in[0];  // [B,S,H]
    const float* map = (const float*)d_in[1];  // [B,N,S]
    const float* len = (const float*)d_in[2];  // [B,N]
    float* out = (float*)d_out;                // [B,N,H]

    // zero accumulation target (harness poisons d_out to 0xAA before each launch)
    hipMemsetAsync(out, 0, (size_t)out_size * sizeof(float), stream);

    dim3 grid(NWG);     // 256 blocks = 1 per CU, 8 waves each
    dim3 block(512);
    hipLaunchKernelGGL(mean_pool_gemm, grid, block, 0, stream, doc, map, len, out);
}